// Round 17
// baseline (558.211 us; speedup 1.0000x reference)
//
#include <hip/hip_runtime.h>
#include <cstdint>

#define D_MODEL 1024
#define ATTN    64
#define NTOPK   32
#define NCAND   40
#define NMETA   33
#define SEQ     4096
#define NROWS   8192
#define CHUNK   1024
#define NCHUNK  8
#define CAP     512

typedef unsigned int u32;
typedef __attribute__((ext_vector_type(8))) short short8;
typedef __attribute__((ext_vector_type(4))) float f32x4;

__device__ __forceinline__ unsigned short f2bf(float f) {
  u32 x = __builtin_bit_cast(u32, f);
  u32 r = (x + 0x7fffu + ((x >> 16) & 1u)) >> 16;
  return (unsigned short)r;
}
__device__ __forceinline__ float bf2f(unsigned short u) {
  return __builtin_bit_cast(float, ((u32)u) << 16);
}
__device__ __forceinline__ u32 mapf(float f) {
  u32 x = __builtin_bit_cast(u32, f);
  return (x & 0x80000000u) ? ~x : (x | 0x80000000u);
}
__device__ __forceinline__ void load_lds16(const void* g, void* l) {
  __builtin_amdgcn_global_load_lds((const __attribute__((address_space(1))) u32*)g,
                                   (__attribute__((address_space(3))) u32*)l, 16, 0, 0);
}

// ---------------- transpose Wv/Wo -> bf16 [N][K] ----------------
__global__ __launch_bounds__(256) void transpose_bf16(const float* __restrict__ Wv,
                                                      const float* __restrict__ Wo,
                                                      unsigned short* __restrict__ Wvt,
                                                      unsigned short* __restrict__ Wot) {
  __shared__ float tile[32][33];
  const float* W = blockIdx.z ? Wo : Wv;
  unsigned short* Wt = blockIdx.z ? Wot : Wvt;
  int n0 = blockIdx.x * 32, k0 = blockIdx.y * 32;
  int tx = threadIdx.x & 31, ty = threadIdx.x >> 5;
#pragma unroll
  for (int i = 0; i < 4; ++i)
    tile[ty + i * 8][tx] = W[(size_t)(k0 + ty + i * 8) * D_MODEL + n0 + tx];
  __syncthreads();
#pragma unroll
  for (int i = 0; i < 4; ++i)
    Wt[(size_t)(n0 + ty + i * 8) * D_MODEL + k0 + tx] = f2bf(tile[tx][ty + i * 8]);
}

// ---------------- Q/K projection (r14-proven: 55us, 0 conflicts) ----------
// BIT-FROZEN math: per output, single f32 accumulator, ascending k, fmaf each step,
// bias last. 16 rows/block, 512 blocks. Do NOT change rows/block (r16: 8 rows/block
// doubled staging-per-FMA -> +40%), do NOT vectorize xs reads (r13), do NOT fuse
// via dynamic LDS (r13/r15: 5.7e7 conflicts, 3-5x slowdown).
__global__ __launch_bounds__(256) void qk_proj(const float* __restrict__ x,
                                               const float* __restrict__ Wq,
                                               const float* __restrict__ Wk,
                                               const float* __restrict__ bq,
                                               const float* __restrict__ bk,
                                               float* __restrict__ Qf,
                                               float* __restrict__ Kf,
                                               unsigned short* __restrict__ xb) {
  __shared__ float ws[64 * 128];   // 32 KB, flat [k][col] (k stride 128)
  __shared__ float xs[16][68];     // 4.25 KB
  int m0 = blockIdx.x * 16;
  int t = threadIdx.x;
  int c0 = (t & 31) * 4;   // 0..124
  int r0 = (t >> 5) * 2;   // 0..14
  float acc[2][4] = {};
  for (int kt = 0; kt < D_MODEL / 64; ++kt) {
    {
      int row = t >> 4, kk = (t & 15) * 4;
      float4 v = *(const float4*)(x + (size_t)(m0 + row) * D_MODEL + kt * 64 + kk);
      *(float4*)&xs[row][kk] = v;
      ushort4 o;
      o.x = f2bf(v.x); o.y = f2bf(v.y); o.z = f2bf(v.z); o.w = f2bf(v.w);
      *(ushort4*)(xb + (size_t)(m0 + row) * D_MODEL + kt * 64 + kk) = o;
    }
    {
#pragma unroll
      for (int q = 0; q < 8; ++q) {
        int F = (t + 256 * q) * 4;   // float index in [64][128]
        int row = F >> 7;
        int col = F & 127;
        const float* src = (col < 64)
            ? (Wq + (size_t)(kt * 64 + row) * ATTN + col)
            : (Wk + (size_t)(kt * 64 + row) * ATTN + (col - 64));
        *(float4*)&ws[F] = *(const float4*)src;
      }
    }
    __syncthreads();
#pragma unroll
    for (int k = 0; k < 64; ++k) {
      float4 w4 = *(const float4*)&ws[k * 128 + c0];
      float wv[4] = {w4.x, w4.y, w4.z, w4.w};
      float x0 = xs[r0][k], x1 = xs[r0 + 1][k];
#pragma unroll
      for (int j = 0; j < 4; ++j) acc[0][j] = fmaf(x0, wv[j], acc[0][j]);
#pragma unroll
      for (int j = 0; j < 4; ++j) acc[1][j] = fmaf(x1, wv[j], acc[1][j]);
    }
    __syncthreads();
  }
  bool isQ = c0 < 64;
  int cc = c0 & 63;
  const float* bias = isQ ? bq : bk;
  float* dst = isQ ? Qf : Kf;
  float4 bb = *(const float4*)(bias + cc);
#pragma unroll
  for (int i = 0; i < 2; ++i) {
    float4 v;
    v.x = acc[i][0] + bb.x; v.y = acc[i][1] + bb.y;
    v.z = acc[i][2] + bb.z; v.w = acc[i][3] + bb.w;
    *(float4*)(dst + (size_t)(m0 + r0 + i) * ATTN + cc) = v;
  }
}

// ---------------- bf16 MFMA GEMM, XCD-aware 1D decomposition ----------------
template <int OUT_BF16>
__global__ __launch_bounds__(256) void gemm_bt(const unsigned short* __restrict__ A,
                                               const unsigned short* __restrict__ Bt,
                                               const float* __restrict__ bias,
                                               void* __restrict__ Cout) {
  const int K = D_MODEL, N = D_MODEL;
  __shared__ __align__(16) unsigned short As[128 * 32];
  __shared__ __align__(16) unsigned short Bs[128 * 32];
  int lin = blockIdx.x;
  int xcd = lin & 7;
  int seq = lin >> 3;
  int m0 = (xcd * 8 + (seq >> 3)) * 128;
  int n0 = (seq & 7) * 128;
  int t = threadIdx.x;
  int w = t >> 6, lane = t & 63;
  int wr = w >> 1, wc = w & 1;
  int frow = lane & 15, kgrp = lane >> 4;
  f32x4 acc[4][4] = {};
  for (int kt = 0; kt < K / 32; ++kt) {
#pragma unroll
    for (int r = 0; r < 2; ++r) {
      int o = (r * 4 + w) * 1024 + lane * 16;
      int row = o >> 6;
      int kb = o & 63;
      load_lds16(A + (size_t)(m0 + row) * K + kt * 32 + (kb >> 1), As + (r * 4 + w) * 512);
      load_lds16(Bt + (size_t)(n0 + row) * K + kt * 32 + (kb >> 1), Bs + (r * 4 + w) * 512);
    }
    __syncthreads();
    short8 af[4], bfr[4];
#pragma unroll
    for (int i = 0; i < 4; ++i) {
      af[i]  = *(const short8*)(As + (wr * 64 + i * 16 + frow) * 32 + kgrp * 8);
      bfr[i] = *(const short8*)(Bs + (wc * 64 + i * 16 + frow) * 32 + kgrp * 8);
    }
#pragma unroll
    for (int i = 0; i < 4; ++i)
#pragma unroll
      for (int j = 0; j < 4; ++j)
        acc[i][j] = __builtin_amdgcn_mfma_f32_16x16x32_bf16(af[i], bfr[j], acc[i][j], 0, 0, 0);
    __syncthreads();
  }
  int crow0 = m0 + wr * 64;
  int ccol0 = n0 + wc * 64;
#pragma unroll
  for (int i = 0; i < 4; ++i)
#pragma unroll
    for (int j = 0; j < 4; ++j) {
      int col = ccol0 + j * 16 + (lane & 15);
      float b = bias[col];
#pragma unroll
      for (int v = 0; v < 4; ++v) {
        int row = crow0 + i * 16 + (lane >> 4) * 4 + v;
        float val = acc[i][j][v] + b;
        if (OUT_BF16)
          ((unsigned short*)Cout)[(size_t)row * N + col] = f2bf(val);
        else
          ((float*)Cout)[(size_t)row * N + col] = val;
      }
    }
}

// ---------- shared-memory structs for score/topk (STATIC union in merged kernel) ----
struct ScoreSmem { float Qk[ATTN][68]; float Kk[ATTN][68]; };   // 34816 B
struct TopkSmem {
  float s[SEQ];
  u32 hist[2048];
  u32 tsum[256];
  u32 binB, cumB;
  int candC;
  float candV[CAP];
  int   candI[CAP];
  float g31s, g32s;
};                                                              // ~29.7 KB
union USmem { ScoreSmem sc; TopkSmem tk; };

// ---------------- score GEMM body (BIT-FROZEN): v2 k-major, CHUNK=1024 ----------
__device__ void score_body(const float* __restrict__ Qf, const float* __restrict__ Kf,
                           float* __restrict__ Sout, int chunk, ScoreSmem& sm, int g) {
  int b = chunk >> 2;            // 4 chunks of 1024 per batch
  int n0 = (g & 63) * 64;
  int m0 = (g >> 6) * 64;        // 16 m-tiles
  int t = threadIdx.x;
  {
    int row = t & 63, cg = (t >> 6) * 16;
    const float* qsrc = Qf + (size_t)(chunk * CHUNK + m0 + row) * ATTN + cg;
    const float* ksrc = Kf + (size_t)(b * SEQ + n0 + row) * ATTN + cg;
#pragma unroll
    for (int m = 0; m < 4; ++m) {
      float4 q4 = *(const float4*)(qsrc + m * 4);
      float4 k4 = *(const float4*)(ksrc + m * 4);
      sm.Qk[cg + m * 4 + 0][row] = q4.x; sm.Qk[cg + m * 4 + 1][row] = q4.y;
      sm.Qk[cg + m * 4 + 2][row] = q4.z; sm.Qk[cg + m * 4 + 3][row] = q4.w;
      sm.Kk[cg + m * 4 + 0][row] = k4.x; sm.Kk[cg + m * 4 + 1][row] = k4.y;
      sm.Kk[cg + m * 4 + 2][row] = k4.z; sm.Kk[cg + m * 4 + 3][row] = k4.w;
    }
  }
  __syncthreads();
  int r0 = (t >> 4) * 4, c0 = (t & 15) * 4;
  float acc[4][4] = {};
  for (int k = 0; k < ATTN; ++k) {
    float4 q4 = *(const float4*)&sm.Qk[k][r0];
    float4 k4 = *(const float4*)&sm.Kk[k][c0];
    float qv[4] = {q4.x, q4.y, q4.z, q4.w};
    float kv[4] = {k4.x, k4.y, k4.z, k4.w};
#pragma unroll
    for (int i = 0; i < 4; ++i)
#pragma unroll
      for (int j = 0; j < 4; ++j) acc[i][j] = fmaf(qv[i], kv[j], acc[i][j]);
  }
#pragma unroll
  for (int i = 0; i < 4; ++i) {
    float4 v;
    v.x = acc[i][0] * 0.125f; v.y = acc[i][1] * 0.125f;
    v.z = acc[i][2] * 0.125f; v.w = acc[i][3] * 0.125f;
    *(float4*)(Sout + (size_t)(m0 + r0 + i) * SEQ + n0 + c0) = v;
  }
}

// ---------------- top-k body (BIT-FROZEN selection), CHUNK=1024 ----------
__device__ void topk_body(const float* __restrict__ S, int* __restrict__ srtIx,
                          float* __restrict__ srtSc, float* __restrict__ gaps,
                          int chunk, TopkSmem& sm, int rloc) {
  int t = threadIdx.x;
  int rglob = chunk * CHUNK + rloc;
  const float* Srow = S + (size_t)rloc * SEQ;
#pragma unroll
  for (int i = 0; i < 4; ++i) {
    float4 v = *(const float4*)(Srow + t * 4 + i * 1024);
    sm.s[t * 4 + i * 1024]     = v.x;
    sm.s[t * 4 + i * 1024 + 1] = v.y;
    sm.s[t * 4 + i * 1024 + 2] = v.z;
    sm.s[t * 4 + i * 1024 + 3] = v.w;
  }
  if (t == 0) sm.candC = 0;
  for (int i = t; i < 2048; i += 256) sm.hist[i] = 0;
  __syncthreads();
  for (int i = 0; i < 16; ++i) {
    u32 u = mapf(sm.s[t + i * 256]);
    atomicAdd(&sm.hist[u >> 21], 1u);
  }
  __syncthreads();
  const int R = NCAND;
  {
    u32 sum = 0;
#pragma unroll
    for (int b = 0; b < 8; ++b) sum += sm.hist[t * 8 + b];
    sm.tsum[t] = sum;
  }
  __syncthreads();
  for (int off = 1; off < 256; off <<= 1) {
    u32 v = (t + off < 256) ? sm.tsum[t + off] : 0u;
    __syncthreads();
    sm.tsum[t] += v;
    __syncthreads();
  }
  {
    u32 c = (t < 255) ? sm.tsum[t + 1] : 0u;
    for (int b = 7; b >= 0; --b) {
      u32 h = sm.hist[t * 8 + b];
      u32 cw = c + h;
      if (cw >= (u32)R && c < (u32)R) { sm.binB = (u32)(t * 8 + b); sm.cumB = cw; }
      c = cw;
    }
  }
  __syncthreads();
  u32 low;
  if (sm.cumB <= CAP) {
    low = sm.binB << 21;
  } else {
    u32 B1 = sm.binB;
    u32 A1 = sm.cumB - sm.hist[B1];
    __syncthreads();
    for (int i = t; i < 2048; i += 256) sm.hist[i] = 0;
    __syncthreads();
    for (int i = 0; i < 16; ++i) {
      u32 u = mapf(sm.s[t + i * 256]);
      if ((u >> 21) == B1) atomicAdd(&sm.hist[(u >> 10) & 0x7FFu], 1u);
    }
    __syncthreads();
    int R2 = R - (int)A1;
    {
      u32 sum = 0;
#pragma unroll
      for (int b = 0; b < 8; ++b) sum += sm.hist[t * 8 + b];
      sm.tsum[t] = sum;
    }
    __syncthreads();
    for (int off = 1; off < 256; off <<= 1) {
      u32 v = (t + off < 256) ? sm.tsum[t + off] : 0u;
      __syncthreads();
      sm.tsum[t] += v;
      __syncthreads();
    }
    {
      u32 c = (t < 255) ? sm.tsum[t + 1] : 0u;
      for (int b = 7; b >= 0; --b) {
        u32 h = sm.hist[t * 8 + b];
        u32 cw = c + h;
        if (cw >= (u32)R2 && c < (u32)R2) sm.binB = (u32)(t * 8 + b);
        c = cw;
      }
    }
    __syncthreads();
    low = (B1 << 21) | (sm.binB << 10);
  }
  __syncthreads();
  for (int i = 0; i < 16; ++i) {
    int j = t + i * 256;
    u32 u = mapf(sm.s[j]);
    if (u >= low) {
      int slot = atomicAdd(&sm.candC, 1);
      if (slot < CAP) { sm.candV[slot] = sm.s[j]; sm.candI[slot] = j; }
    }
  }
  __syncthreads();
  int C = sm.candC < CAP ? sm.candC : CAP;
  for (int c = t; c < C; c += 256) {
    float v = sm.candV[c];
    int idx = sm.candI[c];
    int rank = 0;
    for (int j = 0; j < C; ++j) {
      float vj = sm.candV[j];
      int ij = sm.candI[j];
      if (vj > v || (vj == v && ij < idx)) ++rank;
    }
    if (rank < NMETA) {
      srtIx[(size_t)rglob * NMETA + rank] = idx;
      srtSc[(size_t)rglob * NMETA + rank] = v;
    }
    if (rank == 31) sm.g31s = v;
    if (rank == 32) sm.g32s = v;
  }
  __syncthreads();
  if (t == 0) gaps[rglob] = sm.g31s - sm.g32s;
}

// ---------------- standalone wrappers (STATIC LDS) ----------------
__global__ __launch_bounds__(256) void score_k(const float* Qf, const float* Kf,
                                               float* Sout, int chunk) {
  __shared__ ScoreSmem sm;
  score_body(Qf, Kf, Sout, chunk, sm, blockIdx.x);
}

__global__ __launch_bounds__(256) void topk_k(const float* S, int* srtIx, float* srtSc,
                                              float* gaps, int chunk) {
  __shared__ TopkSmem sm;
  topk_body(S, srtIx, srtSc, gaps, chunk, sm, blockIdx.x);
}

// merged: even bid -> score(c+1) into Scn; odd bid -> topk(c) from Scc. STATIC union.
__global__ __launch_bounds__(256) void scoretopk(const float* Qf, const float* Kf,
                                                 float* Scn, const float* Scc,
                                                 int* srtIx, float* srtSc, float* gaps,
                                                 int c) {
  __shared__ USmem sm;
  int bid = blockIdx.x;
  if ((bid & 1) == 0)
    score_body(Qf, Kf, Scn, c + 1, sm.sc, bid >> 1);
  else
    topk_body(Scc, srtIx, srtSc, gaps, c, sm.tk, bid >> 1);
}

// ---------------- global argmin of the rank-31/32 gap (BIT-FROZEN) ----------
__global__ __launch_bounds__(256) void argmin_gap(const float* __restrict__ gaps,
                                                  int* __restrict__ flag) {
  __shared__ float mg[256];
  __shared__ int mr[256];
  int t = threadIdx.x;
  float best = 1e30f;
  int bestr = 0;
  for (int r = t; r < NROWS; r += 256) {
    float g = gaps[r];
    if (g < best) { best = g; bestr = r; }
  }
  mg[t] = best; mr[t] = bestr;
  __syncthreads();
  for (int off = 128; off; off >>= 1) {
    if (t < off) {
      if (mg[t + off] < mg[t] || (mg[t + off] == mg[t] && mr[t + off] < mr[t])) {
        mg[t] = mg[t + off]; mr[t] = mr[t + off];
      }
    }
    __syncthreads();
  }
  if (t == 0) *flag = mr[0];
}

// ---------------- softmax + bf16 V gather; XCD-batch affinity (BIT-FROZEN) ----------
__global__ __launch_bounds__(256) void gather_out(const int* __restrict__ flagrow,
                                                  const int* __restrict__ srtIx,
                                                  const float* __restrict__ srtSc,
                                                  const unsigned short* __restrict__ Vb,
                                                  unsigned short* __restrict__ attnVb) {
  __shared__ int six[NTOPK];
  __shared__ float ssc[NTOPK];
  __shared__ float selw[NTOPK];
  int t = threadIdx.x;
  int bid = blockIdx.x;
  int xcd = bid & 7;
  int rglob = ((xcd >> 2) << 12) + ((bid >> 3) << 2) + (xcd & 3);
  int b = rglob >> 12;
  int fr = *flagrow;
  if (t < NTOPK) {
    int src = (t == 31 && rglob == fr) ? 32 : t;
    six[t] = srtIx[(size_t)rglob * NMETA + src];
    ssc[t] = srtSc[(size_t)rglob * NMETA + src];
  }
  __syncthreads();
  if (t == 0) {
    float mx = ssc[0];
    for (int i = 1; i < NTOPK; ++i) mx = fmaxf(mx, ssc[i]);
    double Z = 0.0;
    double w[NTOPK];
    for (int i = 0; i < NTOPK; ++i) { w[i] = exp((double)ssc[i] - (double)mx); Z += w[i]; }
    double inv = 1.0 / Z;
    for (int i = 0; i < NTOPK; ++i) selw[i] = (float)(w[i] * inv);
  }
  __syncthreads();
  const unsigned short* Vbase = Vb + (size_t)b * SEQ * D_MODEL;
  float o0 = 0.f, o1 = 0.f, o2 = 0.f, o3 = 0.f;
  int d0 = t * 4;
#pragma unroll 4
  for (int i = 0; i < NTOPK; ++i) {
    ushort4 v = *(const ushort4*)(Vbase + (size_t)six[i] * D_MODEL + d0);
    float w = selw[i];
    o0 = fmaf(w, bf2f(v.x), o0);
    o1 = fmaf(w, bf2f(v.y), o1);
    o2 = fmaf(w, bf2f(v.z), o2);
    o3 = fmaf(w, bf2f(v.w), o3);
  }
  ushort4 ov;
  ov.x = f2bf(o0); ov.y = f2bf(o1); ov.z = f2bf(o2); ov.w = f2bf(o3);
  *(ushort4*)(attnVb + (size_t)rglob * D_MODEL + d0) = ov;
}

extern "C" void kernel_launch(void* const* d_in, const int* in_sizes, int n_in,
                              void* d_out, int out_size, void* d_ws, size_t ws_size,
                              hipStream_t stream) {
  const float* x  = (const float*)d_in[0];
  const float* Wq = (const float*)d_in[1];
  const float* bq = (const float*)d_in[2];
  const float* Wk = (const float*)d_in[3];
  const float* bk = (const float*)d_in[4];
  const float* Wv = (const float*)d_in[5];
  const float* bv = (const float*)d_in[6];
  const float* Wo = (const float*)d_in[7];
  const float* bo = (const float*)d_in[8];

  uint8_t* ws = (uint8_t*)d_ws;
  const size_t MB = 1u << 20;
  unsigned short* xb     = (unsigned short*)(ws);            // 16MB
  unsigned short* Vb     = (unsigned short*)(ws + 16 * MB);  // 16MB
  unsigned short* attnVb = (unsigned short*)(ws + 32 * MB);  // 16MB
  unsigned short* Wvt    = (unsigned short*)(ws + 48 * MB);  // 2MB
  unsigned short* Wot    = (unsigned short*)(ws + 50 * MB);  // 2MB
  float* Qf    = (float*)(ws + 52 * MB);                     // 2MB
  float* Kf    = (float*)(ws + 54 * MB);                     // 2MB
  float* srtSc = (float*)(ws + 56 * MB);                     // ~1.04MB
  int*   srtIx = (int*)(ws + 58 * MB);                       // ~1.04MB
  float* gaps  = (float*)(ws + 60 * MB);                     // 32KB
  int*   flag  = (int*)(ws + 60 * MB + 256 * 1024);          // 4B  (<61MB total)
  // double-buffered 16MB score halves inside d_out (fully overwritten by final gemm)
  float* Sc0 = (float*)d_out;
  float* Sc1 = (float*)((uint8_t*)d_out + 16 * MB);

  transpose_bf16<<<dim3(32, 32, 2), dim3(256), 0, stream>>>(Wv, Wo, Wvt, Wot);
  qk_proj<<<dim3(NROWS / 16), dim3(256), 0, stream>>>(x, Wq, Wk, bq, bk, Qf, Kf, xb);
  gemm_bt<1><<<dim3(512), dim3(256), 0, stream>>>(xb, Wvt, bv, Vb);
  score_k<<<dim3(1024), dim3(256), 0, stream>>>(Qf, Kf, Sc0, 0);
  for (int c = 0; c < NCHUNK - 1; ++c) {
    float* Scn = ((c + 1) & 1) ? Sc1 : Sc0;
    float* Scc = (c & 1) ? Sc1 : Sc0;
    scoretopk<<<dim3(2048), dim3(256), 0, stream>>>(Qf, Kf, Scn, Scc,
                                                    srtIx, srtSc, gaps, c);
  }
  topk_k<<<dim3(1024), dim3(256), 0, stream>>>(Sc1, srtIx, srtSc, gaps, NCHUNK - 1);
  argmin_gap<<<dim3(1), dim3(256), 0, stream>>>(gaps, flag);
  gather_out<<<dim3(NROWS), dim3(256), 0, stream>>>(flag, srtIx, srtSc, Vb, attnVb);
  gemm_bt<0><<<dim3(512), dim3(256), 0, stream>>>(attnVb, Wot, bo, (float*)d_out);
}

// Round 18
// 409.262 us; speedup vs baseline: 1.3639x; 1.3639x over previous
//
#include <hip/hip_runtime.h>
#include <cstdint>

#define D_MODEL 1024
#define ATTN    64
#define NTOPK   32
#define NCAND   40
#define NMETA   33
#define SEQ     4096
#define NROWS   8192
#define CHUNK   2048
#define NCHUNK  4
#define CAP     512

typedef unsigned int u32;
typedef __attribute__((ext_vector_type(8))) short short8;
typedef __attribute__((ext_vector_type(4))) float f32x4;

__device__ __forceinline__ unsigned short f2bf(float f) {
  u32 x = __builtin_bit_cast(u32, f);
  u32 r = (x + 0x7fffu + ((x >> 16) & 1u)) >> 16;
  return (unsigned short)r;
}
__device__ __forceinline__ float bf2f(unsigned short u) {
  return __builtin_bit_cast(float, ((u32)u) << 16);
}
__device__ __forceinline__ u32 mapf(float f) {
  u32 x = __builtin_bit_cast(u32, f);
  return (x & 0x80000000u) ? ~x : (x | 0x80000000u);
}
__device__ __forceinline__ void load_lds16(const void* g, void* l) {
  __builtin_amdgcn_global_load_lds((const __attribute__((address_space(1))) u32*)g,
                                   (__attribute__((address_space(3))) u32*)l, 16, 0, 0);
}

// ---------------- transpose Wv/Wo -> bf16 [N][K] ----------------
__global__ __launch_bounds__(256) void transpose_bf16(const float* __restrict__ Wv,
                                                      const float* __restrict__ Wo,
                                                      unsigned short* __restrict__ Wvt,
                                                      unsigned short* __restrict__ Wot) {
  __shared__ float tile[32][33];
  const float* W = blockIdx.z ? Wo : Wv;
  unsigned short* Wt = blockIdx.z ? Wot : Wvt;
  int n0 = blockIdx.x * 32, k0 = blockIdx.y * 32;
  int tx = threadIdx.x & 31, ty = threadIdx.x >> 5;
#pragma unroll
  for (int i = 0; i < 4; ++i)
    tile[ty + i * 8][tx] = W[(size_t)(k0 + ty + i * 8) * D_MODEL + n0 + tx];
  __syncthreads();
#pragma unroll
  for (int i = 0; i < 4; ++i)
    Wt[(size_t)(n0 + ty + i * 8) * D_MODEL + k0 + tx] = f2bf(tile[tx][ty + i * 8]);
}

// ---------------- Q/K projection (r12/r14-proven: ~55us, 0 conflicts) ----------
// BIT-FROZEN math: per output, single f32 accumulator, ascending k, fmaf each step,
// bias last. 16 rows/block, 512 blocks. Empirically pinned geometry:
//  - 8 rows/block (r16): +40% (staging-per-FMA doubled)
//  - b128 xs broadcast reads (r13): conflict storm
//  - ANY heterogeneous fusion (r13/r15/r17): 3-5x degradation. Keep standalone.
__global__ __launch_bounds__(256) void qk_proj(const float* __restrict__ x,
                                               const float* __restrict__ Wq,
                                               const float* __restrict__ Wk,
                                               const float* __restrict__ bq,
                                               const float* __restrict__ bk,
                                               float* __restrict__ Qf,
                                               float* __restrict__ Kf,
                                               unsigned short* __restrict__ xb) {
  __shared__ float ws[64 * 128];   // 32 KB, flat [k][col] (k stride 128)
  __shared__ float xs[16][68];     // 4.25 KB
  int m0 = blockIdx.x * 16;
  int t = threadIdx.x;
  int c0 = (t & 31) * 4;   // 0..124
  int r0 = (t >> 5) * 2;   // 0..14
  float acc[2][4] = {};
  for (int kt = 0; kt < D_MODEL / 64; ++kt) {
    {
      int row = t >> 4, kk = (t & 15) * 4;
      float4 v = *(const float4*)(x + (size_t)(m0 + row) * D_MODEL + kt * 64 + kk);
      *(float4*)&xs[row][kk] = v;
      ushort4 o;
      o.x = f2bf(v.x); o.y = f2bf(v.y); o.z = f2bf(v.z); o.w = f2bf(v.w);
      *(ushort4*)(xb + (size_t)(m0 + row) * D_MODEL + kt * 64 + kk) = o;
    }
    {
#pragma unroll
      for (int q = 0; q < 8; ++q) {
        int F = (t + 256 * q) * 4;   // float index in [64][128]
        int row = F >> 7;
        int col = F & 127;
        const float* src = (col < 64)
            ? (Wq + (size_t)(kt * 64 + row) * ATTN + col)
            : (Wk + (size_t)(kt * 64 + row) * ATTN + (col - 64));
        *(float4*)&ws[F] = *(const float4*)src;
      }
    }
    __syncthreads();
#pragma unroll
    for (int k = 0; k < 64; ++k) {
      float4 w4 = *(const float4*)&ws[k * 128 + c0];
      float wv[4] = {w4.x, w4.y, w4.z, w4.w};
      float x0 = xs[r0][k], x1 = xs[r0 + 1][k];
#pragma unroll
      for (int j = 0; j < 4; ++j) acc[0][j] = fmaf(x0, wv[j], acc[0][j]);
#pragma unroll
      for (int j = 0; j < 4; ++j) acc[1][j] = fmaf(x1, wv[j], acc[1][j]);
    }
    __syncthreads();
  }
  bool isQ = c0 < 64;
  int cc = c0 & 63;
  const float* bias = isQ ? bq : bk;
  float* dst = isQ ? Qf : Kf;
  float4 bb = *(const float4*)(bias + cc);
#pragma unroll
  for (int i = 0; i < 2; ++i) {
    float4 v;
    v.x = acc[i][0] + bb.x; v.y = acc[i][1] + bb.y;
    v.z = acc[i][2] + bb.z; v.w = acc[i][3] + bb.w;
    *(float4*)(dst + (size_t)(m0 + r0 + i) * ATTN + cc) = v;
  }
}

// ---------------- bf16 MFMA GEMM, XCD-aware 1D decomposition ----------------
template <int OUT_BF16>
__global__ __launch_bounds__(256) void gemm_bt(const unsigned short* __restrict__ A,
                                               const unsigned short* __restrict__ Bt,
                                               const float* __restrict__ bias,
                                               void* __restrict__ Cout) {
  const int K = D_MODEL, N = D_MODEL;
  __shared__ __align__(16) unsigned short As[128 * 32];
  __shared__ __align__(16) unsigned short Bs[128 * 32];
  int lin = blockIdx.x;
  int xcd = lin & 7;
  int seq = lin >> 3;
  int m0 = (xcd * 8 + (seq >> 3)) * 128;
  int n0 = (seq & 7) * 128;
  int t = threadIdx.x;
  int w = t >> 6, lane = t & 63;
  int wr = w >> 1, wc = w & 1;
  int frow = lane & 15, kgrp = lane >> 4;
  f32x4 acc[4][4] = {};
  for (int kt = 0; kt < K / 32; ++kt) {
#pragma unroll
    for (int r = 0; r < 2; ++r) {
      int o = (r * 4 + w) * 1024 + lane * 16;
      int row = o >> 6;
      int kb = o & 63;
      load_lds16(A + (size_t)(m0 + row) * K + kt * 32 + (kb >> 1), As + (r * 4 + w) * 512);
      load_lds16(Bt + (size_t)(n0 + row) * K + kt * 32 + (kb >> 1), Bs + (r * 4 + w) * 512);
    }
    __syncthreads();
    short8 af[4], bfr[4];
#pragma unroll
    for (int i = 0; i < 4; ++i) {
      af[i]  = *(const short8*)(As + (wr * 64 + i * 16 + frow) * 32 + kgrp * 8);
      bfr[i] = *(const short8*)(Bs + (wc * 64 + i * 16 + frow) * 32 + kgrp * 8);
    }
#pragma unroll
    for (int i = 0; i < 4; ++i)
#pragma unroll
      for (int j = 0; j < 4; ++j)
        acc[i][j] = __builtin_amdgcn_mfma_f32_16x16x32_bf16(af[i], bfr[j], acc[i][j], 0, 0, 0);
    __syncthreads();
  }
  int crow0 = m0 + wr * 64;
  int ccol0 = n0 + wc * 64;
#pragma unroll
  for (int i = 0; i < 4; ++i)
#pragma unroll
    for (int j = 0; j < 4; ++j) {
      int col = ccol0 + j * 16 + (lane & 15);
      float b = bias[col];
#pragma unroll
      for (int v = 0; v < 4; ++v) {
        int row = crow0 + i * 16 + (lane >> 4) * 4 + v;
        float val = acc[i][j][v] + b;
        if (OUT_BF16)
          ((unsigned short*)Cout)[(size_t)row * N + col] = f2bf(val);
        else
          ((float*)Cout)[(size_t)row * N + col] = val;
      }
    }
}

// ---------------- score GEMM v2: k-major LDS, f32 sequential FMA, *0.125f -----------
// BIT-FROZEN math: per output, ascending k, single accumulator, same (i,j) FMA order.
__global__ __launch_bounds__(256) void score_gemm(const float* __restrict__ Qf,
                                                  const float* __restrict__ Kf,
                                                  float* __restrict__ Sout, int chunk) {
  __shared__ float Qk[ATTN][68];   // k-major: [k][row]
  __shared__ float Kk[ATTN][68];   // k-major: [k][col]
  int b = chunk >> 1;        // 2 chunks of 2048 per batch
  int n0 = blockIdx.x * 64;
  int m0 = blockIdx.y * 64;
  int t = threadIdx.x;
  {
    int row = t & 63, cg = (t >> 6) * 16;
    const float* qsrc = Qf + (size_t)(chunk * CHUNK + m0 + row) * ATTN + cg;
    const float* ksrc = Kf + (size_t)(b * SEQ + n0 + row) * ATTN + cg;
#pragma unroll
    for (int m = 0; m < 4; ++m) {
      float4 q4 = *(const float4*)(qsrc + m * 4);
      float4 k4 = *(const float4*)(ksrc + m * 4);
      Qk[cg + m * 4 + 0][row] = q4.x; Qk[cg + m * 4 + 1][row] = q4.y;
      Qk[cg + m * 4 + 2][row] = q4.z; Qk[cg + m * 4 + 3][row] = q4.w;
      Kk[cg + m * 4 + 0][row] = k4.x; Kk[cg + m * 4 + 1][row] = k4.y;
      Kk[cg + m * 4 + 2][row] = k4.z; Kk[cg + m * 4 + 3][row] = k4.w;
    }
  }
  __syncthreads();
  int r0 = (t >> 4) * 4, c0 = (t & 15) * 4;
  float acc[4][4] = {};
  for (int k = 0; k < ATTN; ++k) {
    float4 q4 = *(const float4*)&Qk[k][r0];
    float4 k4 = *(const float4*)&Kk[k][c0];
    float qv[4] = {q4.x, q4.y, q4.z, q4.w};
    float kv[4] = {k4.x, k4.y, k4.z, k4.w};
#pragma unroll
    for (int i = 0; i < 4; ++i)
#pragma unroll
      for (int j = 0; j < 4; ++j) acc[i][j] = fmaf(qv[i], kv[j], acc[i][j]);
  }
#pragma unroll
  for (int i = 0; i < 4; ++i) {
    float4 v;
    v.x = acc[i][0] * 0.125f; v.y = acc[i][1] * 0.125f;
    v.z = acc[i][2] * 0.125f; v.w = acc[i][3] * 0.125f;
    *(float4*)(Sout + (size_t)(m0 + r0 + i) * SEQ + n0 + c0) = v;
  }
}

// ---------------- per-row top-k: 2048-bin histogram filter + exact candidate rank ----
__global__ __launch_bounds__(256) void topk_select(const float* __restrict__ S,
                                                   int* __restrict__ srtIx,
                                                   float* __restrict__ srtSc,
                                                   float* __restrict__ gaps,
                                                   int chunk) {
  __shared__ float s[SEQ];
  __shared__ u32 hist[2048];
  __shared__ u32 tsum[256];
  __shared__ u32 binB, cumB;
  __shared__ int candC;
  __shared__ float candV[CAP];
  __shared__ int   candI[CAP];
  __shared__ float g31s, g32s;
  int t = threadIdx.x;
  int rloc = blockIdx.x;
  int rglob = chunk * CHUNK + rloc;
  const float* Srow = S + (size_t)rloc * SEQ;
#pragma unroll
  for (int i = 0; i < 4; ++i) {
    float4 v = *(const float4*)(Srow + t * 4 + i * 1024);
    s[t * 4 + i * 1024]     = v.x;
    s[t * 4 + i * 1024 + 1] = v.y;
    s[t * 4 + i * 1024 + 2] = v.z;
    s[t * 4 + i * 1024 + 3] = v.w;
  }
  if (t == 0) candC = 0;
  for (int i = t; i < 2048; i += 256) hist[i] = 0;
  __syncthreads();
  for (int i = 0; i < 16; ++i) {
    u32 u = mapf(s[t + i * 256]);
    atomicAdd(&hist[u >> 21], 1u);
  }
  __syncthreads();
  const int R = NCAND;
  {
    u32 sum = 0;
#pragma unroll
    for (int b = 0; b < 8; ++b) sum += hist[t * 8 + b];
    tsum[t] = sum;
  }
  __syncthreads();
  for (int off = 1; off < 256; off <<= 1) {
    u32 v = (t + off < 256) ? tsum[t + off] : 0u;
    __syncthreads();
    tsum[t] += v;
    __syncthreads();
  }
  {
    u32 c = (t < 255) ? tsum[t + 1] : 0u;
    for (int b = 7; b >= 0; --b) {
      u32 h = hist[t * 8 + b];
      u32 cw = c + h;
      if (cw >= (u32)R && c < (u32)R) { binB = (u32)(t * 8 + b); cumB = cw; }
      c = cw;
    }
  }
  __syncthreads();
  u32 low;
  if (cumB <= CAP) {
    low = binB << 21;
  } else {
    u32 B1 = binB;
    u32 A1 = cumB - hist[B1];
    __syncthreads();
    for (int i = t; i < 2048; i += 256) hist[i] = 0;
    __syncthreads();
    for (int i = 0; i < 16; ++i) {
      u32 u = mapf(s[t + i * 256]);
      if ((u >> 21) == B1) atomicAdd(&hist[(u >> 10) & 0x7FFu], 1u);
    }
    __syncthreads();
    int R2 = R - (int)A1;
    {
      u32 sum = 0;
#pragma unroll
      for (int b = 0; b < 8; ++b) sum += hist[t * 8 + b];
      tsum[t] = sum;
    }
    __syncthreads();
    for (int off = 1; off < 256; off <<= 1) {
      u32 v = (t + off < 256) ? tsum[t + off] : 0u;
      __syncthreads();
      tsum[t] += v;
      __syncthreads();
    }
    {
      u32 c = (t < 255) ? tsum[t + 1] : 0u;
      for (int b = 7; b >= 0; --b) {
        u32 h = hist[t * 8 + b];
        u32 cw = c + h;
        if (cw >= (u32)R2 && c < (u32)R2) binB = (u32)(t * 8 + b);
        c = cw;
      }
    }
    __syncthreads();
    low = (B1 << 21) | (binB << 10);
  }
  __syncthreads();
  for (int i = 0; i < 16; ++i) {
    int j = t + i * 256;
    u32 u = mapf(s[j]);
    if (u >= low) {
      int slot = atomicAdd(&candC, 1);
      if (slot < CAP) { candV[slot] = s[j]; candI[slot] = j; }
    }
  }
  __syncthreads();
  int C = candC < CAP ? candC : CAP;
  for (int c = t; c < C; c += 256) {
    float v = candV[c];
    int idx = candI[c];
    int rank = 0;
    for (int j = 0; j < C; ++j) {
      float vj = candV[j];
      int ij = candI[j];
      if (vj > v || (vj == v && ij < idx)) ++rank;
    }
    if (rank < NMETA) {
      srtIx[(size_t)rglob * NMETA + rank] = idx;
      srtSc[(size_t)rglob * NMETA + rank] = v;
    }
    if (rank == 31) g31s = v;
    if (rank == 32) g32s = v;
  }
  __syncthreads();
  if (t == 0) gaps[rglob] = g31s - g32s;
}

// ---------------- global argmin of the rank-31/32 gap (BIT-FROZEN) ----------
__global__ __launch_bounds__(256) void argmin_gap(const float* __restrict__ gaps,
                                                  int* __restrict__ flag) {
  __shared__ float mg[256];
  __shared__ int mr[256];
  int t = threadIdx.x;
  float best = 1e30f;
  int bestr = 0;
  for (int r = t; r < NROWS; r += 256) {
    float g = gaps[r];
    if (g < best) { best = g; bestr = r; }
  }
  mg[t] = best; mr[t] = bestr;
  __syncthreads();
  for (int off = 128; off; off >>= 1) {
    if (t < off) {
      if (mg[t + off] < mg[t] || (mg[t + off] == mg[t] && mr[t + off] < mr[t])) {
        mg[t] = mg[t + off]; mr[t] = mr[t + off];
      }
    }
    __syncthreads();
  }
  if (t == 0) *flag = mr[0];
}

// ---------------- softmax + bf16 V gather; XCD-batch affinity (BIT-FROZEN) ----------
__global__ __launch_bounds__(256) void gather_out(const int* __restrict__ flagrow,
                                                  const int* __restrict__ srtIx,
                                                  const float* __restrict__ srtSc,
                                                  const unsigned short* __restrict__ Vb,
                                                  unsigned short* __restrict__ attnVb) {
  __shared__ int six[NTOPK];
  __shared__ float ssc[NTOPK];
  __shared__ float selw[NTOPK];
  int t = threadIdx.x;
  int bid = blockIdx.x;
  int xcd = bid & 7;
  int rglob = ((xcd >> 2) << 12) + ((bid >> 3) << 2) + (xcd & 3);
  int b = rglob >> 12;
  int fr = *flagrow;
  if (t < NTOPK) {
    int src = (t == 31 && rglob == fr) ? 32 : t;
    six[t] = srtIx[(size_t)rglob * NMETA + src];
    ssc[t] = srtSc[(size_t)rglob * NMETA + src];
  }
  __syncthreads();
  if (t == 0) {
    float mx = ssc[0];
    for (int i = 1; i < NTOPK; ++i) mx = fmaxf(mx, ssc[i]);
    double Z = 0.0;
    double w[NTOPK];
    for (int i = 0; i < NTOPK; ++i) { w[i] = exp((double)ssc[i] - (double)mx); Z += w[i]; }
    double inv = 1.0 / Z;
    for (int i = 0; i < NTOPK; ++i) selw[i] = (float)(w[i] * inv);
  }
  __syncthreads();
  const unsigned short* Vbase = Vb + (size_t)b * SEQ * D_MODEL;
  float o0 = 0.f, o1 = 0.f, o2 = 0.f, o3 = 0.f;
  int d0 = t * 4;
#pragma unroll 4
  for (int i = 0; i < NTOPK; ++i) {
    ushort4 v = *(const ushort4*)(Vbase + (size_t)six[i] * D_MODEL + d0);
    float w = selw[i];
    o0 = fmaf(w, bf2f(v.x), o0);
    o1 = fmaf(w, bf2f(v.y), o1);
    o2 = fmaf(w, bf2f(v.z), o2);
    o3 = fmaf(w, bf2f(v.w), o3);
  }
  ushort4 ov;
  ov.x = f2bf(o0); ov.y = f2bf(o1); ov.z = f2bf(o2); ov.w = f2bf(o3);
  *(ushort4*)(attnVb + (size_t)rglob * D_MODEL + d0) = ov;
}

extern "C" void kernel_launch(void* const* d_in, const int* in_sizes, int n_in,
                              void* d_out, int out_size, void* d_ws, size_t ws_size,
                              hipStream_t stream) {
  const float* x  = (const float*)d_in[0];
  const float* Wq = (const float*)d_in[1];
  const float* bq = (const float*)d_in[2];
  const float* Wk = (const float*)d_in[3];
  const float* bk = (const float*)d_in[4];
  const float* Wv = (const float*)d_in[5];
  const float* bv = (const float*)d_in[6];
  const float* Wo = (const float*)d_in[7];
  const float* bo = (const float*)d_in[8];

  uint8_t* ws = (uint8_t*)d_ws;
  const size_t MB = 1u << 20;
  unsigned short* xb     = (unsigned short*)(ws);            // 16MB
  unsigned short* Vb     = (unsigned short*)(ws + 16 * MB);  // 16MB
  unsigned short* attnVb = (unsigned short*)(ws + 32 * MB);  // 16MB
  unsigned short* Wvt    = (unsigned short*)(ws + 48 * MB);  // 2MB
  unsigned short* Wot    = (unsigned short*)(ws + 50 * MB);  // 2MB
  float* Qf    = (float*)(ws + 52 * MB);                     // 2MB
  float* Kf    = (float*)(ws + 54 * MB);                     // 2MB
  float* srtSc = (float*)(ws + 56 * MB);                     // ~1.04MB
  int*   srtIx = (int*)(ws + 58 * MB);                       // ~1.04MB
  float* gaps  = (float*)(ws + 60 * MB);                     // 32KB
  int*   flag  = (int*)(ws + 60 * MB + 256 * 1024);          // 4B  (<61MB total)
  float* Sc    = (float*)d_out;  // 2048*4096*4 = 32MB score scratch (fully overwritten later)

  transpose_bf16<<<dim3(32, 32, 2), dim3(256), 0, stream>>>(Wv, Wo, Wvt, Wot);
  qk_proj<<<dim3(NROWS / 16), dim3(256), 0, stream>>>(x, Wq, Wk, bq, bk, Qf, Kf, xb);
  gemm_bt<1><<<dim3(512), dim3(256), 0, stream>>>(xb, Wvt, bv, Vb);
  for (int c = 0; c < NCHUNK; ++c) {
    score_gemm<<<dim3(SEQ / 64, CHUNK / 64), dim3(256), 0, stream>>>(Qf, Kf, Sc, c);
    topk_select<<<dim3(CHUNK), dim3(256), 0, stream>>>(Sc, srtIx, srtSc, gaps, c);
  }
  argmin_gap<<<dim3(1), dim3(256), 0, stream>>>(gaps, flag);
  gather_out<<<dim3(NROWS), dim3(256), 0, stream>>>(flag, srtIx, srtSc, Vb, attnVb);
  gemm_bt<0><<<dim3(512), dim3(256), 0, stream>>>(attnVb, Wot, bo, (float*)d_out);
}